// Round 5
// baseline (260.767 us; speedup 1.0000x reference)
//
#include <hip/hip_runtime.h>
#include <math.h>

#define BB 2
#define NN 4096
#define TOT (BB * NN)  // 8192 rows
#define DIM 768
#define QSTRIDE 20  // 8 (q head0) + 8 (q head1) + w0' + w1' + 2 pad
#define SCALE 0.35355339059327373f  // 8^-0.5, folded into w at qproj
#define QBLOCKS 683  // ceil(8192 / 12)

// ---------------------------------------------------------------------------
// proj: fused qproj + kproj, (row, col) lane assignment — each lane owns one
// output element and loops the full dim in-lane. No LDS, no butterflies.
//   q-blocks [0,683): wave = 3 rows x 18 cols (lanes 0..53). Weight loads
//     Wq[k*18+c]: 18 consecutive floats x3 row-replica -> 1-2 lines/instr.
//   k-blocks [683,939): wave = 8 rows x 8 cols (all 64 lanes). Wk[k*8+c]:
//     32 B window = 1 line/instr. + 2D sinusoidal PE per-lane.
// x read as per-lane float4 (row-replicated lanes coalesce); 4 partial accs
// break the fmaf dependence chain.
// qd row layout (stride 20): [q0(8), q1(8), w0*SCALE, w1*SCALE, pad(2)]
//   qw col c -> slot: c<8 -> c ; c==8 -> 16 ; 9<=c<17 -> c-1 ; c==17 -> 17
// ---------------------------------------------------------------------------
__global__ __launch_bounds__(256) void proj_kernel(const float* __restrict__ qt,
                                                   const float* __restrict__ kt,
                                                   const float* __restrict__ Wq,
                                                   const float* __restrict__ Wk,
                                                   const int* __restrict__ hp,
                                                   const int* __restrict__ wp,
                                                   float* __restrict__ qd,
                                                   float* __restrict__ kd) {
  const int tid = threadIdx.x;
  const int lane = tid & 63;
  const int wv = tid >> 6;

  if (blockIdx.x < QBLOCKS) {
    // ---------------- qproj: 12 rows per block ----------------
    const int r = lane / 18;       // 0..2 valid, lanes 54..63 give r==3
    const int c = lane - r * 18;   // 0..17
    const int row = (blockIdx.x * 4 + wv) * 3 + r;
    const bool valid = (r < 3) && (row < TOT);
    const float* xr = qt + (size_t)(valid ? row : 0) * DIM;
    const float* wc = Wq + c;

    float a0 = 0.f, a1 = 0.f, a2 = 0.f, a3 = 0.f;
#pragma unroll 4
    for (int k4 = 0; k4 < DIM / 4; ++k4) {
      const float4 xv = *(const float4*)(xr + k4 * 4);
      const float w0 = wc[(k4 * 4 + 0) * 18];
      const float w1 = wc[(k4 * 4 + 1) * 18];
      const float w2 = wc[(k4 * 4 + 2) * 18];
      const float w3 = wc[(k4 * 4 + 3) * 18];
      a0 = fmaf(xv.x, w0, a0);
      a1 = fmaf(xv.y, w1, a1);
      a2 = fmaf(xv.z, w2, a2);
      a3 = fmaf(xv.w, w3, a3);
    }
    float v = (a0 + a1) + (a2 + a3);

    int slot;
    if (c < 8) slot = c;
    else if (c == 8) slot = 16;
    else if (c == 17) slot = 17;
    else slot = c - 1;
    if (c == 8 || c == 17) v *= SCALE;
    if (valid) qd[(size_t)row * QSTRIDE + slot] = v;
  } else {
    // ---------------- kproj: 32 rows per block ----------------
    const int r = lane >> 3;   // 0..7
    const int c = lane & 7;    // 0..7
    const int row = ((blockIdx.x - QBLOCKS) * 4 + wv) * 8 + r;  // < 8192 exact
    const float* xr = kt + (size_t)row * DIM;
    const float* wc = Wk + c;

    float a0 = 0.f, a1 = 0.f, a2 = 0.f, a3 = 0.f;
#pragma unroll 4
    for (int k4 = 0; k4 < DIM / 4; ++k4) {
      const float4 xv = *(const float4*)(xr + k4 * 4);
      const float w0 = wc[(k4 * 4 + 0) * 8];
      const float w1 = wc[(k4 * 4 + 1) * 8];
      const float w2 = wc[(k4 * 4 + 2) * 8];
      const float w3 = wc[(k4 * 4 + 3) * 8];
      a0 = fmaf(xv.x, w0, a0);
      a1 = fmaf(xv.y, w1, a1);
      a2 = fmaf(xv.z, w2, a2);
      a3 = fmaf(xv.w, w3, a3);
    }
    float v = (a0 + a1) + (a2 + a3);

    // 2D sinusoidal PE for element (row % NN, col c)
    const int h = hp[0];
    const int w = wp[0];
    const int n = row & (NN - 1);
    const int yi = n / w;
    const int xi = n - yi * w;
    const int hd = (h - 1) > 1 ? (h - 1) : 1;
    const int wd = (w - 1) > 1 ? (w - 1) : 1;
    const float base = (c < 4) ? ((float)yi / (float)hd) : ((float)xi / (float)wd);
    const float sc = (c < 4) ? (float)h : (float)w;
    const float fr = (c & 2) ? 0.01f : 1.0f;
    const float ang = base * fr * sc;
    const float pe = (c & 1) ? cosf(ang) : sinf(ang);

    kd[(size_t)row * 8 + c] = v + pe;  // 64 consecutive floats: coalesced
  }
}

// ---------------------------------------------------------------------------
// scores: out[b,q,k] = w0'*relu(<q0,k>) + w1'*relu(<q1,k>) + bias  (w' = w*SCALE)
// Wave = 64 consecutive keys (lane = key) x 8 query rows.
//   k: 2 coalesced float4 loads per lane (8 VGPRs, reused x8 rows).
//   q: wave-uniform pointer (readfirstlane) -> scalar s_load path, q values
//      consumed as the scalar operand of v_fma (no VMEM transactions).
//   stores: 8 per wave, each 64 lanes x 4 B = fully coalesced 256 B.
// ---------------------------------------------------------------------------
__global__ __launch_bounds__(256) void scores_kernel(const float* __restrict__ qd,
                                                     const float* __restrict__ kd,
                                                     const float* __restrict__ bias,
                                                     float* __restrict__ out) {
  const int lane = threadIdx.x & 63;
  const int wv = __builtin_amdgcn_readfirstlane(threadIdx.x >> 6);
  const int kb = blockIdx.x;  // 64-key tile
  const int qb = blockIdx.y;  // 32-query tile (4 waves x 8 rows)
  const int b  = blockIdx.z;

  const float* kp = kd + ((size_t)b * NN + kb * 64 + lane) * 8;
  const float4 k0 = *(const float4*)kp;
  const float4 k1 = *(const float4*)(kp + 4);
  const float sb = bias[0];

  const int row0 = qb * 32 + wv * 8;
  const float* qp = qd + ((size_t)b * NN + row0) * QSTRIDE;
  float* op = out + ((size_t)b * NN + row0) * (size_t)NN + (size_t)(kb * 64 + lane);

#pragma unroll
  for (int rr = 0; rr < 8; ++rr) {
    const float* q = qp + rr * QSTRIDE;
    float d0 = q[0] * k0.x;
    d0 = fmaf(q[1], k0.y, d0);
    d0 = fmaf(q[2], k0.z, d0);
    d0 = fmaf(q[3], k0.w, d0);
    d0 = fmaf(q[4], k1.x, d0);
    d0 = fmaf(q[5], k1.y, d0);
    d0 = fmaf(q[6], k1.z, d0);
    d0 = fmaf(q[7], k1.w, d0);
    float d1 = q[8] * k0.x;
    d1 = fmaf(q[9],  k0.y, d1);
    d1 = fmaf(q[10], k0.z, d1);
    d1 = fmaf(q[11], k0.w, d1);
    d1 = fmaf(q[12], k1.x, d1);
    d1 = fmaf(q[13], k1.y, d1);
    d1 = fmaf(q[14], k1.z, d1);
    d1 = fmaf(q[15], k1.w, d1);
    d0 = fmaxf(d0, 0.f);
    d1 = fmaxf(d1, 0.f);
    op[(size_t)rr * NN] = fmaf(q[16], d0, fmaf(q[17], d1, sb));
  }
}

// ---------------------------------------------------------------------------
extern "C" void kernel_launch(void* const* d_in, const int* in_sizes, int n_in,
                              void* d_out, int out_size, void* d_ws, size_t ws_size,
                              hipStream_t stream) {
  const float* qt = (const float*)d_in[0];  // (2, 4096, 768)
  const float* kt = (const float*)d_in[1];  // (2, 4096, 768)
  const float* Wq = (const float*)d_in[2];  // (768, 18)
  const float* Wk = (const float*)d_in[3];  // (768, 8)
  const float* sb = (const float*)d_in[4];  // (1,1,1)
  const int* hp = (const int*)d_in[5];      // height (64)
  const int* wp = (const int*)d_in[6];      // width  (64)

  float* qd = (float*)d_ws;                      // 8192 * 20 floats = 640 KB
  float* kd = qd + (size_t)TOT * QSTRIDE;        // 8192 * 8 floats  = 256 KB
  float* outp = (float*)d_out;                   // (2, 4096, 4096) fp32

  // q: 683 blocks (12 rows each) + k: 256 blocks (32 rows each)
  proj_kernel<<<QBLOCKS + 256, 256, 0, stream>>>(qt, kt, Wq, Wk, hp, wp, qd, kd);
  // 64 key-tiles x 128 query-tiles x 2 batches
  scores_kernel<<<dim3(64, NN / 32, BB), 256, 0, stream>>>(qd, kd, sb, outp);
}